// Round 9
// baseline (572.121 us; speedup 1.0000x reference)
//
#include <hip/hip_runtime.h>

#define NV   20000
#define MAXN 16

// ---------------------------------------------------------------------------
// Mask dtype detection (bool may arrive as int32 / byte / float32).
// flag: 0 = int32 words, 2 = float32 pattern, 1 = byte bool.
// ---------------------------------------------------------------------------
__global__ void detect_mask_kind(const unsigned int* __restrict__ m,
                                 int* __restrict__ flag) {
    if (threadIdx.x == 0 && blockIdx.x == 0) {
        int allint = 1, allflt = 1;
        #pragma unroll 8
        for (int k = 0; k < 64; ++k) {
            unsigned w = m[k];
            if (!(w == 0u || w == 1u)) allint = 0;
            if (!(w == 0u || w == 0x3F800000u)) allflt = 0;
        }
        *flag = allint ? 0 : (allflt ? 2 : 1);
    }
}

// ---------------------------------------------------------------------------
// One-time weight combine: for each thread slot t=(c,i) produce 8 rows of 8
// (WQ, WK, W0, W1o0, W1o1, W2o0, W2o1, W2o2) = 64 floats, contiguous per t.
// 64KB table, L2-resident, shared by all 20000 main blocks.
// ---------------------------------------------------------------------------
__global__ void compute_weights(const float* __restrict__ rr,
                                const float* __restrict__ vb0,
                                const float* __restrict__ vb1,
                                const float* __restrict__ vb2,
                                const float* __restrict__ qc,
                                const float* __restrict__ kc,
                                const float* __restrict__ w0p,
                                const float* __restrict__ w1p,
                                const float* __restrict__ w2p,
                                float4* __restrict__ wt) {
    const int t = threadIdx.x;
    const int c = t & 31;
    const int i = t >> 5;
    float WQr[8], WKr[8], W0r[8], W1r0[8], W1r1[8], W2r0[8], W2r1[8], W2r2[8];
    #pragma unroll
    for (int j = 0; j < 8; ++j) {
        WQr[j] = 0.f; WKr[j] = 0.f; W0r[j] = 0.f; W1r0[j] = 0.f;
        W1r1[j] = 0.f; W2r0[j] = 0.f; W2r1[j] = 0.f; W2r2[j] = 0.f;
    }
    #pragma unroll
    for (int b = 0; b < 8; ++b) {
        const float qcb = qc[c * 8 + b];
        const float kcb = kc[c * 8 + b];
        const float w0b = w0p[c * 8 + b];
        const float w1b = w1p[c * 8 + b];
        const float w2b = w2p[c * 8 + b];
        const float* rrb = rr  + b * 64  + i * 8;
        const float* z0  = vb0 + b * 64  + i * 8;
        const float* z1  = vb1 + b * 128 + i * 8;   // [b][o][i][j]
        const float* z2  = vb2 + b * 192 + i * 8;
        #pragma unroll
        for (int j = 0; j < 8; ++j) {
            const float r = rrb[j];
            WQr[j]  = fmaf(qcb, r, WQr[j]);
            WKr[j]  = fmaf(kcb, r, WKr[j]);
            W0r[j]  = fmaf(w0b, z0[j],       W0r[j]);
            W1r0[j] = fmaf(w1b, z1[j],       W1r0[j]);
            W1r1[j] = fmaf(w1b, z1[64 + j],  W1r1[j]);
            W2r0[j] = fmaf(w2b, z2[j],       W2r0[j]);
            W2r1[j] = fmaf(w2b, z2[64 + j],  W2r1[j]);
            W2r2[j] = fmaf(w2b, z2[128 + j], W2r2[j]);
        }
    }
    float4* o = wt + t * 16;
    o[ 0] = *(const float4*)&WQr[0];  o[ 1] = *(const float4*)&WQr[4];
    o[ 2] = *(const float4*)&WKr[0];  o[ 3] = *(const float4*)&WKr[4];
    o[ 4] = *(const float4*)&W0r[0];  o[ 5] = *(const float4*)&W0r[4];
    o[ 6] = *(const float4*)&W1r0[0]; o[ 7] = *(const float4*)&W1r0[4];
    o[ 8] = *(const float4*)&W1r1[0]; o[ 9] = *(const float4*)&W1r1[4];
    o[10] = *(const float4*)&W2r0[0]; o[11] = *(const float4*)&W2r0[4];
    o[12] = *(const float4*)&W2r1[0]; o[13] = *(const float4*)&W2r1[4];
    o[14] = *(const float4*)&W2r2[0]; o[15] = *(const float4*)&W2r2[4];
}

__device__ __forceinline__ float dot8a(const float* __restrict__ w,
                                       const float* __restrict__ f) {
    float s = w[0] * f[0];
    #pragma unroll
    for (int j = 1; j < 8; ++j) s = fmaf(w[j], f[j], s);
    return s;
}

__device__ __forceinline__ float dot8f4(const float4& a, const float4& b,
                                        const float* __restrict__ f) {
    return fmaf(a.x, f[0], fmaf(a.y, f[1], fmaf(a.z, f[2], fmaf(a.w, f[3],
           fmaf(b.x, f[4], fmaf(b.y, f[5], fmaf(b.z, f[6], b.w * f[7])))))));
}

// Phase-split, branch-free, ILP-batched:
//  phase 1: thread (c,i) transports neighbors n=2i,2i+1 (f' *= mask), LDS.
//  phase 2: groups of 4 neighbors — 16 indep ds_read_b64, 4 indep butterfly
//           reduction chains (shuffles are DS ops; ILP=4 hides their latency
//           — R8's branchy per-neighbor serial chain left VALUBusy at 48%),
//           then 24 indep value dots on live f registers.
__global__ void __launch_bounds__(256, 3)
ge_attn_kernel(const float* __restrict__ x,
               const int*   __restrict__ neighbors,
               const void*  __restrict__ maskp,
               const float* __restrict__ ptm,
               const float* __restrict__ rpu,
               const float4* __restrict__ wt,
               const int*   __restrict__ mflag,
               float*       __restrict__ out) {
    const int t = threadIdx.x;
    const int c = t & 31;   // channel
    const int i = t >> 5;   // rep index 0..7
    const int w = t >> 6;   // wave id 0..3
    const int mf = *mflag;

    // per-thread combined weight rows: 64 floats, pinned (AGPR/VGPR resident).
    // layout: [WQ 0..7][WK 8..15][W0 16..23][W1o0 24..31][W1o1 32..39]
    //         [W2o0 40..47][W2o1 48..55][W2o2 56..63]
    float W[64];
    {
        const float4* wp = wt + t * 16;
        #pragma unroll
        for (int r = 0; r < 16; ++r) {
            const float4 q = wp[r];
            W[r * 4 + 0] = q.x; W[r * 4 + 1] = q.y;
            W[r * 4 + 2] = q.z; W[r * 4 + 3] = q.w;
        }
        #pragma unroll
        for (int r = 0; r < 64; ++r)
            asm volatile("" : "+v"(W[r]));   // anti-remat / anti-reload pin
    }

    // shared transported features: [n][j-pair][c], float2 per slot = 16KB
    __shared__ __align__(16) float2 fsh[16][4][32];
    __shared__ __align__(16) float  swv[16][4];

    const int v  = blockIdx.x;
    const int vq = v * 16;

    // uniform loads: neighbor ids + mask as float multiplier
    int nb[16];
    float mfl[16];
    #pragma unroll
    for (int n = 0; n < 16; ++n) {
        nb[n] = neighbors[vq + n];
        int mm;
        if (mf == 0)      mm = (((const int*)maskp)[vq + n] != 0);
        else if (mf == 1) mm = (((const unsigned char*)maskp)[vq + n] != 0);
        else              mm = (((const float*)maskp)[vq + n] != 0.0f);
        mfl[n] = mm ? 1.f : 0.f;
    }

    // ---- phase 1 (branch-free): transport n=2i and 2i+1, mask-scaled ----
    #pragma unroll
    for (int sub = 0; sub < 2; ++sub) {
        const int n = 2 * i + sub;
        const float m = mfl[n];
        float xn[8];
        {
            const float* xnp = x + (size_t)nb[n] * 256 + c * 8;
            *(float4*)&xn[0] = *(const float4*)xnp;
            *(float4*)&xn[4] = *(const float4*)(xnp + 4);
        }
        const float4* P4 = (const float4*)(ptm + (size_t)(vq + n) * 64);
        #pragma unroll
        for (int j2 = 0; j2 < 4; ++j2) {
            float2 fo;
            fo.x = dot8f4(P4[4 * j2 + 0], P4[4 * j2 + 1], xn) * m;
            fo.y = dot8f4(P4[4 * j2 + 2], P4[4 * j2 + 3], xn) * m;
            fsh[n][j2][c] = fo;
        }
    }

    // K[i] for this thread's i, reduced over c in-wave (overlaps phase 1)
    float kreg;
    {
        float xc[8];
        const float* xv = x + (size_t)v * 256 + c * 8;
        *(float4*)&xc[0] = *(const float4*)xv;
        *(float4*)&xc[4] = *(const float4*)(xv + 4);
        float kp = dot8a(&W[8], xc);
        kp += __shfl_xor(kp, 1);
        kp += __shfl_xor(kp, 2);
        kp += __shfl_xor(kp, 4);
        kp += __shfl_xor(kp, 8);
        kp += __shfl_xor(kp, 16);
        kreg = kp;
    }

    __syncthreads();   // fsh published

    // ---- phase 2: groups of 4 neighbors, branch-free ----
    float vals[16];
    float acc = 0.f, ssum = 0.f;

    #pragma unroll
    for (int g = 0; g < 4; ++g) {
        float f0[8], f1[8], f2[8], f3[8];
        #pragma unroll
        for (int j2 = 0; j2 < 4; ++j2) {
            const float2 a = fsh[4 * g + 0][j2][c];
            const float2 b = fsh[4 * g + 1][j2][c];
            const float2 d = fsh[4 * g + 2][j2][c];
            const float2 e = fsh[4 * g + 3][j2][c];
            f0[2 * j2] = a.x; f0[2 * j2 + 1] = a.y;
            f1[2 * j2] = b.x; f1[2 * j2 + 1] = b.y;
            f2[2 * j2] = d.x; f2[2 * j2 + 1] = d.y;
            f3[2 * j2] = e.x; f3[2 * j2 + 1] = e.y;
        }
        // 4 independent Q-partials + 4-way-ILP butterfly over c
        float q0 = dot8a(&W[0], f0);
        float q1 = dot8a(&W[0], f1);
        float q2 = dot8a(&W[0], f2);
        float q3 = dot8a(&W[0], f3);
        #pragma unroll
        for (int d = 1; d <= 16; d <<= 1) {
            q0 += __shfl_xor(q0, d);
            q1 += __shfl_xor(q1, d);
            q2 += __shfl_xor(q2, d);
            q3 += __shfl_xor(q3, d);
        }
        float r0 = fmaxf(q0 + kreg, 0.f);
        float r1 = fmaxf(q1 + kreg, 0.f);
        float r2 = fmaxf(q2 + kreg, 0.f);
        float r3 = fmaxf(q3 + kreg, 0.f);
        const float s0 = (r0 + __shfl_xor(r0, 32)) * mfl[4 * g + 0];
        const float s1 = (r1 + __shfl_xor(r1, 32)) * mfl[4 * g + 1];
        const float s2 = (r2 + __shfl_xor(r2, 32)) * mfl[4 * g + 2];
        const float s3 = (r3 + __shfl_xor(r3, 32)) * mfl[4 * g + 3];
        if ((t & 63) == 0) {
            swv[4 * g + 0][w] = s0;
            swv[4 * g + 1][w] = s1;
            swv[4 * g + 2][w] = s2;
            swv[4 * g + 3][w] = s3;
        }
        // value scalars: 6 dots + u-poly per neighbor, f still in registers
        #pragma unroll
        for (int k = 0; k < 4; ++k) {
            const int n = 4 * g + k;
            const float* f = (k == 0) ? f0 : (k == 1) ? f1 : (k == 2) ? f2 : f3;
            const float u0 = rpu[(size_t)(vq + n) * 2];
            const float u1 = rpu[(size_t)(vq + n) * 2 + 1];
            const float y0 = dot8a(&W[16], f);
            const float y1 = dot8a(&W[24], f);
            const float y2 = dot8a(&W[32], f);
            const float y3 = dot8a(&W[40], f);
            const float y4 = dot8a(&W[48], f);
            const float y5 = dot8a(&W[56], f);
            float val = fmaf(u0, y1, y0);
            val = fmaf(u1, y2, val);
            val = fmaf(u0 * u0, y3, val);
            val = fmaf(2.f * u0 * u1, y4, val);
            val = fmaf(u1 * u1, y5, val);
            vals[n] = val;
        }
    }

    __syncthreads();   // swv published

    #pragma unroll
    for (int n = 0; n < 16; ++n) {
        const float4 sv = *(const float4*)&swv[n][0];
        const float sc = 0.125f * (sv.x + sv.y + sv.z + sv.w);
        ssum += sc;
        acc  = fmaf(sc, vals[n], acc);
    }
    out[(size_t)v * 256 + c * 8 + i] = acc / fmaxf(ssum, 1e-8f);
}

extern "C" void kernel_launch(void* const* d_in, const int* in_sizes, int n_in,
                              void* d_out, int out_size, void* d_ws, size_t ws_size,
                              hipStream_t stream) {
    const float* x         = (const float*)d_in[0];
    const int*   neighbors = (const int*)d_in[1];
    const void*  maskp     = d_in[2];
    const float* ptm       = (const float*)d_in[3];
    const float* rpu       = (const float*)d_in[4];
    const float* rr        = (const float*)d_in[5];
    const float* vb0       = (const float*)d_in[6];
    const float* vb1       = (const float*)d_in[7];
    const float* vb2       = (const float*)d_in[8];
    const float* qc        = (const float*)d_in[9];
    const float* kc        = (const float*)d_in[10];
    const float* w0p       = (const float*)d_in[11];
    const float* w1p       = (const float*)d_in[12];
    const float* w2p       = (const float*)d_in[13];
    float* out = (float*)d_out;

    int*    flag = (int*)d_ws;
    float4* wtab = (float4*)((char*)d_ws + 1024);   // 64KB table

    detect_mask_kind<<<1, 64, 0, stream>>>((const unsigned int*)maskp, flag);
    compute_weights<<<1, 256, 0, stream>>>(rr, vb0, vb1, vb2,
                                           qc, kc, w0p, w1p, w2p, wtab);
    ge_attn_kernel<<<NV, 256, 0, stream>>>(x, neighbors, maskp, ptm, rpu,
                                           wtab, flag, out);
}

// Round 10
// 539.642 us; speedup vs baseline: 1.0602x; 1.0602x over previous
//
#include <hip/hip_runtime.h>

#define NV   20000
#define MAXN 16

// ---------------------------------------------------------------------------
// Mask dtype detection (bool may arrive as int32 / byte / float32).
// flag: 0 = int32 words, 2 = float32 pattern, 1 = byte bool.
// ---------------------------------------------------------------------------
__global__ void detect_mask_kind(const unsigned int* __restrict__ m,
                                 int* __restrict__ flag) {
    if (threadIdx.x == 0 && blockIdx.x == 0) {
        int allint = 1, allflt = 1;
        #pragma unroll 8
        for (int k = 0; k < 64; ++k) {
            unsigned w = m[k];
            if (!(w == 0u || w == 1u)) allint = 0;
            if (!(w == 0u || w == 0x3F800000u)) allflt = 0;
        }
        *flag = allint ? 0 : (allflt ? 2 : 1);
    }
}

// ---------------------------------------------------------------------------
// One-time weight combine: for each thread slot t=(c,i) produce 8 rows of 8
// (WQ, WK, W0, W1o0, W1o1, W2o0, W2o1, W2o2) = 64 floats, contiguous per t.
// 64KB table, L2-resident, shared by all 20000 main blocks.
// ---------------------------------------------------------------------------
__global__ void compute_weights(const float* __restrict__ rr,
                                const float* __restrict__ vb0,
                                const float* __restrict__ vb1,
                                const float* __restrict__ vb2,
                                const float* __restrict__ qc,
                                const float* __restrict__ kc,
                                const float* __restrict__ w0p,
                                const float* __restrict__ w1p,
                                const float* __restrict__ w2p,
                                float4* __restrict__ wt) {
    const int t = threadIdx.x;
    const int c = t & 31;
    const int i = t >> 5;
    float WQr[8], WKr[8], W0r[8], W1r0[8], W1r1[8], W2r0[8], W2r1[8], W2r2[8];
    #pragma unroll
    for (int j = 0; j < 8; ++j) {
        WQr[j] = 0.f; WKr[j] = 0.f; W0r[j] = 0.f; W1r0[j] = 0.f;
        W1r1[j] = 0.f; W2r0[j] = 0.f; W2r1[j] = 0.f; W2r2[j] = 0.f;
    }
    #pragma unroll
    for (int b = 0; b < 8; ++b) {
        const float qcb = qc[c * 8 + b];
        const float kcb = kc[c * 8 + b];
        const float w0b = w0p[c * 8 + b];
        const float w1b = w1p[c * 8 + b];
        const float w2b = w2p[c * 8 + b];
        const float* rrb = rr  + b * 64  + i * 8;
        const float* z0  = vb0 + b * 64  + i * 8;
        const float* z1  = vb1 + b * 128 + i * 8;   // [b][o][i][j]
        const float* z2  = vb2 + b * 192 + i * 8;
        #pragma unroll
        for (int j = 0; j < 8; ++j) {
            const float r = rrb[j];
            WQr[j]  = fmaf(qcb, r, WQr[j]);
            WKr[j]  = fmaf(kcb, r, WKr[j]);
            W0r[j]  = fmaf(w0b, z0[j],       W0r[j]);
            W1r0[j] = fmaf(w1b, z1[j],       W1r0[j]);
            W1r1[j] = fmaf(w1b, z1[64 + j],  W1r1[j]);
            W2r0[j] = fmaf(w2b, z2[j],       W2r0[j]);
            W2r1[j] = fmaf(w2b, z2[64 + j],  W2r1[j]);
            W2r2[j] = fmaf(w2b, z2[128 + j], W2r2[j]);
        }
    }
    float4* o = wt + t * 16;
    o[ 0] = *(const float4*)&WQr[0];  o[ 1] = *(const float4*)&WQr[4];
    o[ 2] = *(const float4*)&WKr[0];  o[ 3] = *(const float4*)&WKr[4];
    o[ 4] = *(const float4*)&W0r[0];  o[ 5] = *(const float4*)&W0r[4];
    o[ 6] = *(const float4*)&W1r0[0]; o[ 7] = *(const float4*)&W1r0[4];
    o[ 8] = *(const float4*)&W1r1[0]; o[ 9] = *(const float4*)&W1r1[4];
    o[10] = *(const float4*)&W2r0[0]; o[11] = *(const float4*)&W2r0[4];
    o[12] = *(const float4*)&W2r1[0]; o[13] = *(const float4*)&W2r1[4];
    o[14] = *(const float4*)&W2r2[0]; o[15] = *(const float4*)&W2r2[4];
}

__device__ __forceinline__ float dot8a(const float* __restrict__ w,
                                       const float* __restrict__ f) {
    float s = w[0] * f[0];
    #pragma unroll
    for (int j = 1; j < 8; ++j) s = fmaf(w[j], f[j], s);
    return s;
}

__device__ __forceinline__ float dot8f4(const float4& a, const float4& b,
                                        const float* __restrict__ f) {
    return fmaf(a.x, f[0], fmaf(a.y, f[1], fmaf(a.z, f[2], fmaf(a.w, f[3],
           fmaf(b.x, f[4], fmaf(b.y, f[5], fmaf(b.z, f[6], b.w * f[7])))))));
}

// Phase-split, fully branch-free:
//  phase 1: thread (c,i) transports neighbors n=2i,2i+1 (f' *= mask) to LDS.
//  phase 2: straight-line per-neighbor bodies with NO mask branches — R8's
//           `if(!live) continue` fenced the scheduler so the serial 5-shuffle
//           reduction chain (~150cy of DS latency) couldn't overlap across
//           neighbors; R9's explicit 4-batch spilled (WRITE 1.14GB). Branch-
//           free per-neighbor code lets the compiler software-pipeline 2-3
//           iterations at moderate register pressure.
__global__ void __launch_bounds__(256, 3)
ge_attn_kernel(const float* __restrict__ x,
               const int*   __restrict__ neighbors,
               const void*  __restrict__ maskp,
               const float* __restrict__ ptm,
               const float* __restrict__ rpu,
               const float4* __restrict__ wt,
               const int*   __restrict__ mflag,
               float*       __restrict__ out) {
    const int t = threadIdx.x;
    const int c = t & 31;   // channel
    const int i = t >> 5;   // rep index 0..7
    const int w = t >> 6;   // wave id 0..3
    const int mf = *mflag;

    // per-thread combined weight rows: 64 floats, pinned (AGPR/VGPR resident).
    // layout: [WQ 0..7][WK 8..15][W0 16..23][W1o0 24..31][W1o1 32..39]
    //         [W2o0 40..47][W2o1 48..55][W2o2 56..63]
    float W[64];
    {
        const float4* wp = wt + t * 16;
        #pragma unroll
        for (int r = 0; r < 16; ++r) {
            const float4 q = wp[r];
            W[r * 4 + 0] = q.x; W[r * 4 + 1] = q.y;
            W[r * 4 + 2] = q.z; W[r * 4 + 3] = q.w;
        }
        #pragma unroll
        for (int r = 0; r < 64; ++r)
            asm volatile("" : "+v"(W[r]));   // anti-remat / anti-reload pin
    }

    // shared transported features: [n][j-pair][c], float2 per slot = 16KB
    __shared__ __align__(16) float2 fsh[16][4][32];
    __shared__ __align__(16) float  swv[16][4];

    const int v  = blockIdx.x;
    const int vq = v * 16;

    // uniform loads: neighbor ids + mask as float multiplier
    int nb[16];
    float mfl[16];
    #pragma unroll
    for (int n = 0; n < 16; ++n) {
        nb[n] = neighbors[vq + n];
        int mm;
        if (mf == 0)      mm = (((const int*)maskp)[vq + n] != 0);
        else if (mf == 1) mm = (((const unsigned char*)maskp)[vq + n] != 0);
        else              mm = (((const float*)maskp)[vq + n] != 0.0f);
        mfl[n] = mm ? 1.f : 0.f;
    }

    // ---- phase 1 (branch-free): transport n=2i and 2i+1, mask-scaled ----
    #pragma unroll
    for (int sub = 0; sub < 2; ++sub) {
        const int n = 2 * i + sub;
        const float m = mfl[n];
        float xn[8];
        {
            const float* xnp = x + (size_t)nb[n] * 256 + c * 8;
            *(float4*)&xn[0] = *(const float4*)xnp;
            *(float4*)&xn[4] = *(const float4*)(xnp + 4);
        }
        const float4* P4 = (const float4*)(ptm + (size_t)(vq + n) * 64);
        #pragma unroll
        for (int j2 = 0; j2 < 4; ++j2) {
            float2 fo;
            fo.x = dot8f4(P4[4 * j2 + 0], P4[4 * j2 + 1], xn) * m;
            fo.y = dot8f4(P4[4 * j2 + 2], P4[4 * j2 + 3], xn) * m;
            fsh[n][j2][c] = fo;
        }
    }

    // K[i] for this thread's i, reduced over c in-wave (overlaps phase 1)
    float kreg;
    {
        float xc[8];
        const float* xv = x + (size_t)v * 256 + c * 8;
        *(float4*)&xc[0] = *(const float4*)xv;
        *(float4*)&xc[4] = *(const float4*)(xv + 4);
        float kp = dot8a(&W[8], xc);
        kp += __shfl_xor(kp, 1);
        kp += __shfl_xor(kp, 2);
        kp += __shfl_xor(kp, 4);
        kp += __shfl_xor(kp, 8);
        kp += __shfl_xor(kp, 16);
        kreg = kp;
    }

    __syncthreads();   // fsh published

    // ---- phase 2: branch-free per-neighbor bodies (compiler pipelines) ----
    float vals[16];
    float acc = 0.f, ssum = 0.f;

    #pragma unroll
    for (int n = 0; n < 16; ++n) {
        float f[8];
        #pragma unroll
        for (int j2 = 0; j2 < 4; ++j2) {
            const float2 t2 = fsh[n][j2][c];
            f[2 * j2]     = t2.x;
            f[2 * j2 + 1] = t2.y;
        }
        // score partial: Q[i] over c, relu, i-pair sum, mask multiply.
        // dead neighbors: f==0 -> q==0, but relu(kreg) != 0, so mfl zeroes s.
        float q = dot8a(&W[0], f);
        q += __shfl_xor(q, 1);
        q += __shfl_xor(q, 2);
        q += __shfl_xor(q, 4);
        q += __shfl_xor(q, 8);
        q += __shfl_xor(q, 16);
        const float r = fmaxf(q + kreg, 0.f);
        const float s = (r + __shfl_xor(r, 32)) * mfl[n];
        if ((t & 63) == 0) swv[n][w] = s;
        // value scalar for this (c,i): 6 dots + u-poly (0 for dead: f==0)
        const float u0 = rpu[(size_t)(vq + n) * 2];
        const float u1 = rpu[(size_t)(vq + n) * 2 + 1];
        const float y0 = dot8a(&W[16], f);
        const float y1 = dot8a(&W[24], f);
        const float y2 = dot8a(&W[32], f);
        const float y3 = dot8a(&W[40], f);
        const float y4 = dot8a(&W[48], f);
        const float y5 = dot8a(&W[56], f);
        float val = fmaf(u0, y1, y0);
        val = fmaf(u1, y2, val);
        val = fmaf(u0 * u0, y3, val);
        val = fmaf(2.f * u0 * u1, y4, val);
        val = fmaf(u1 * u1, y5, val);
        vals[n] = val;
    }

    __syncthreads();   // swv published

    #pragma unroll
    for (int n = 0; n < 16; ++n) {
        const float4 sv = *(const float4*)&swv[n][0];
        const float sc = 0.125f * (sv.x + sv.y + sv.z + sv.w);
        ssum += sc;
        acc  = fmaf(sc, vals[n], acc);
    }
    out[(size_t)v * 256 + c * 8 + i] = acc / fmaxf(ssum, 1e-8f);
}

extern "C" void kernel_launch(void* const* d_in, const int* in_sizes, int n_in,
                              void* d_out, int out_size, void* d_ws, size_t ws_size,
                              hipStream_t stream) {
    const float* x         = (const float*)d_in[0];
    const int*   neighbors = (const int*)d_in[1];
    const void*  maskp     = d_in[2];
    const float* ptm       = (const float*)d_in[3];
    const float* rpu       = (const float*)d_in[4];
    const float* rr        = (const float*)d_in[5];
    const float* vb0       = (const float*)d_in[6];
    const float* vb1       = (const float*)d_in[7];
    const float* vb2       = (const float*)d_in[8];
    const float* qc        = (const float*)d_in[9];
    const float* kc        = (const float*)d_in[10];
    const float* w0p       = (const float*)d_in[11];
    const float* w1p       = (const float*)d_in[12];
    const float* w2p       = (const float*)d_in[13];
    float* out = (float*)d_out;

    int*    flag = (int*)d_ws;
    float4* wtab = (float4*)((char*)d_ws + 1024);   // 64KB table

    detect_mask_kind<<<1, 64, 0, stream>>>((const unsigned int*)maskp, flag);
    compute_weights<<<1, 256, 0, stream>>>(rr, vb0, vb1, vb2,
                                           qc, kc, w0p, w1p, w2p, wtab);
    ge_attn_kernel<<<NV, 256, 0, stream>>>(x, neighbors, maskp, ptm, rpu,
                                           wtab, flag, out);
}

// Round 11
// 412.253 us; speedup vs baseline: 1.3878x; 1.3090x over previous
//
#include <hip/hip_runtime.h>

#define NV   20000
#define MAXN 16

// ---------------------------------------------------------------------------
// Mask dtype detection (bool may arrive as int32 / byte / float32).
// flag: 0 = int32 words, 2 = float32 pattern, 1 = byte bool.
// ---------------------------------------------------------------------------
__global__ void detect_mask_kind(const unsigned int* __restrict__ m,
                                 int* __restrict__ flag) {
    if (threadIdx.x == 0 && blockIdx.x == 0) {
        int allint = 1, allflt = 1;
        #pragma unroll 8
        for (int k = 0; k < 64; ++k) {
            unsigned w = m[k];
            if (!(w == 0u || w == 1u)) allint = 0;
            if (!(w == 0u || w == 0x3F800000u)) allflt = 0;
        }
        *flag = allint ? 0 : (allflt ? 2 : 1);
    }
}

// ---------------------------------------------------------------------------
// One-time weight combine: for each thread slot t=(c,i) produce 8 rows of 8
// (WQ, WK, W0, W1o0, W1o1, W2o0, W2o1, W2o2) = 64 floats, contiguous per t.
// 64KB table, L2-resident, shared by all 20000 main blocks.
// ---------------------------------------------------------------------------
__global__ void compute_weights(const float* __restrict__ rr,
                                const float* __restrict__ vb0,
                                const float* __restrict__ vb1,
                                const float* __restrict__ vb2,
                                const float* __restrict__ qc,
                                const float* __restrict__ kc,
                                const float* __restrict__ w0p,
                                const float* __restrict__ w1p,
                                const float* __restrict__ w2p,
                                float4* __restrict__ wt) {
    const int t = threadIdx.x;
    const int c = t & 31;
    const int i = t >> 5;
    float WQr[8], WKr[8], W0r[8], W1r0[8], W1r1[8], W2r0[8], W2r1[8], W2r2[8];
    #pragma unroll
    for (int j = 0; j < 8; ++j) {
        WQr[j] = 0.f; WKr[j] = 0.f; W0r[j] = 0.f; W1r0[j] = 0.f;
        W1r1[j] = 0.f; W2r0[j] = 0.f; W2r1[j] = 0.f; W2r2[j] = 0.f;
    }
    #pragma unroll
    for (int b = 0; b < 8; ++b) {
        const float qcb = qc[c * 8 + b];
        const float kcb = kc[c * 8 + b];
        const float w0b = w0p[c * 8 + b];
        const float w1b = w1p[c * 8 + b];
        const float w2b = w2p[c * 8 + b];
        const float* rrb = rr  + b * 64  + i * 8;
        const float* z0  = vb0 + b * 64  + i * 8;
        const float* z1  = vb1 + b * 128 + i * 8;   // [b][o][i][j]
        const float* z2  = vb2 + b * 192 + i * 8;
        #pragma unroll
        for (int j = 0; j < 8; ++j) {
            const float r = rrb[j];
            WQr[j]  = fmaf(qcb, r, WQr[j]);
            WKr[j]  = fmaf(kcb, r, WKr[j]);
            W0r[j]  = fmaf(w0b, z0[j],       W0r[j]);
            W1r0[j] = fmaf(w1b, z1[j],       W1r0[j]);
            W1r1[j] = fmaf(w1b, z1[64 + j],  W1r1[j]);
            W2r0[j] = fmaf(w2b, z2[j],       W2r0[j]);
            W2r1[j] = fmaf(w2b, z2[64 + j],  W2r1[j]);
            W2r2[j] = fmaf(w2b, z2[128 + j], W2r2[j]);
        }
    }
    float4* o = wt + t * 16;
    o[ 0] = *(const float4*)&WQr[0];  o[ 1] = *(const float4*)&WQr[4];
    o[ 2] = *(const float4*)&WKr[0];  o[ 3] = *(const float4*)&WKr[4];
    o[ 4] = *(const float4*)&W0r[0];  o[ 5] = *(const float4*)&W0r[4];
    o[ 6] = *(const float4*)&W1r0[0]; o[ 7] = *(const float4*)&W1r0[4];
    o[ 8] = *(const float4*)&W1r1[0]; o[ 9] = *(const float4*)&W1r1[4];
    o[10] = *(const float4*)&W2r0[0]; o[11] = *(const float4*)&W2r0[4];
    o[12] = *(const float4*)&W2r1[0]; o[13] = *(const float4*)&W2r1[4];
    o[14] = *(const float4*)&W2r2[0]; o[15] = *(const float4*)&W2r2[4];
}

__device__ __forceinline__ float dot8a(const float* __restrict__ w,
                                       const float* __restrict__ f) {
    float s = w[0] * f[0];
    #pragma unroll
    for (int j = 1; j < 8; ++j) s = fmaf(w[j], f[j], s);
    return s;
}

__device__ __forceinline__ float dot8f4(const float4& a, const float4& b,
                                        const float* __restrict__ f) {
    return fmaf(a.x, f[0], fmaf(a.y, f[1], fmaf(a.z, f[2], fmaf(a.w, f[3],
           fmaf(b.x, f[4], fmaf(b.y, f[5], fmaf(b.z, f[6], b.w * f[7])))))));
}

// Two-lean-pass kernel. R9/R10 lesson: phase-2 forms holding >2 neighbors of
// state spill (WRITE_SIZE 0.6-1.1GB); branchy forms serialize (VALUBusy 48%).
// Pass A computes ONLY scores (live set ~12 regs); pass B re-reads f from LDS
// and accumulates sc*val directly (live ~20 regs, no vals[16]). Both
// branch-free, #pragma unroll 4 (bounded ILP, bounded hoisting). No
// runtime-indexed register arrays anywhere (masks live in LDS smask).
__global__ void __launch_bounds__(256, 3)
ge_attn_kernel(const float* __restrict__ x,
               const int*   __restrict__ neighbors,
               const void*  __restrict__ maskp,
               const float* __restrict__ ptm,
               const float* __restrict__ rpu,
               const float4* __restrict__ wt,
               const int*   __restrict__ mflag,
               float*       __restrict__ out) {
    const int t = threadIdx.x;
    const int c = t & 31;   // channel
    const int i = t >> 5;   // rep index 0..7
    const int w = t >> 6;   // wave id 0..3
    const int mf = *mflag;

    // per-thread combined weight rows: 64 floats, pinned (AGPR/VGPR resident).
    // layout: [WQ 0..7][WK 8..15][W0 16..23][W1o0 24..31][W1o1 32..39]
    //         [W2o0 40..47][W2o1 48..55][W2o2 56..63]
    float W[64];
    {
        const float4* wp = wt + t * 16;
        #pragma unroll
        for (int r = 0; r < 16; ++r) {
            const float4 q = wp[r];
            W[r * 4 + 0] = q.x; W[r * 4 + 1] = q.y;
            W[r * 4 + 2] = q.z; W[r * 4 + 3] = q.w;
        }
        #pragma unroll
        for (int r = 0; r < 64; ++r)
            asm volatile("" : "+v"(W[r]));   // anti-remat / anti-reload pin
    }

    // shared transported features: [n][j-pair][c], float2 per slot = 16KB
    __shared__ __align__(16) float2 fsh[16][4][32];
    __shared__ __align__(16) float  swv[16][4];
    __shared__ float smask[16];

    const int v  = blockIdx.x;
    const int vq = v * 16;

    // mask -> LDS (read per-iteration in pass A; no register array)
    if (t < 16) {
        int mm;
        if (mf == 0)      mm = (((const int*)maskp)[vq + t] != 0);
        else if (mf == 1) mm = (((const unsigned char*)maskp)[vq + t] != 0);
        else              mm = (((const float*)maskp)[vq + t] != 0.0f);
        smask[t] = mm ? 1.f : 0.f;
    }

    // ---- phase 1 (branch-free): transport n=2i and 2i+1, mask-scaled ----
    #pragma unroll
    for (int sub = 0; sub < 2; ++sub) {
        const int n = 2 * i + sub;
        int mm;
        if (mf == 0)      mm = (((const int*)maskp)[vq + n] != 0);
        else if (mf == 1) mm = (((const unsigned char*)maskp)[vq + n] != 0);
        else              mm = (((const float*)maskp)[vq + n] != 0.0f);
        const float m = mm ? 1.f : 0.f;
        const int nbv = neighbors[vq + n];
        float xn[8];
        {
            const float* xnp = x + (size_t)nbv * 256 + c * 8;
            *(float4*)&xn[0] = *(const float4*)xnp;
            *(float4*)&xn[4] = *(const float4*)(xnp + 4);
        }
        const float4* P4 = (const float4*)(ptm + (size_t)(vq + n) * 64);
        #pragma unroll
        for (int j2 = 0; j2 < 4; ++j2) {
            float2 fo;
            fo.x = dot8f4(P4[4 * j2 + 0], P4[4 * j2 + 1], xn) * m;
            fo.y = dot8f4(P4[4 * j2 + 2], P4[4 * j2 + 3], xn) * m;
            fsh[n][j2][c] = fo;
        }
    }

    // K[i] for this thread's i, reduced over c in-wave (overlaps phase 1)
    float kreg;
    {
        float xc[8];
        const float* xv = x + (size_t)v * 256 + c * 8;
        *(float4*)&xc[0] = *(const float4*)xv;
        *(float4*)&xc[4] = *(const float4*)(xv + 4);
        float kp = dot8a(&W[8], xc);
        kp += __shfl_xor(kp, 1);
        kp += __shfl_xor(kp, 2);
        kp += __shfl_xor(kp, 4);
        kp += __shfl_xor(kp, 8);
        kp += __shfl_xor(kp, 16);
        kreg = kp;
    }

    __syncthreads();   // fsh + smask published

    // ---- pass A: scores only (lean: f, q, temps) ----
    #pragma unroll 4
    for (int n = 0; n < 16; ++n) {
        float f[8];
        #pragma unroll
        for (int j2 = 0; j2 < 4; ++j2) {
            const float2 t2 = fsh[n][j2][c];
            f[2 * j2]     = t2.x;
            f[2 * j2 + 1] = t2.y;
        }
        float q = dot8a(&W[0], f);
        q += __shfl_xor(q, 1);
        q += __shfl_xor(q, 2);
        q += __shfl_xor(q, 4);
        q += __shfl_xor(q, 8);
        q += __shfl_xor(q, 16);
        const float r = fmaxf(q + kreg, 0.f);
        const float s = (r + __shfl_xor(r, 32)) * smask[n];
        if ((t & 63) == 0) swv[n][w] = s;
    }

    __syncthreads();   // swv published

    // ---- pass B: values + weighted accumulation (lean: f, y's) ----
    float acc = 0.f, ssum = 0.f;
    #pragma unroll 4
    for (int n = 0; n < 16; ++n) {
        const float4 sv = *(const float4*)&swv[n][0];
        const float sc = 0.125f * (sv.x + sv.y + sv.z + sv.w);
        ssum += sc;
        float f[8];
        #pragma unroll
        for (int j2 = 0; j2 < 4; ++j2) {
            const float2 t2 = fsh[n][j2][c];
            f[2 * j2]     = t2.x;
            f[2 * j2 + 1] = t2.y;
        }
        const float u0 = rpu[(size_t)(vq + n) * 2];
        const float u1 = rpu[(size_t)(vq + n) * 2 + 1];
        const float y0 = dot8a(&W[16], f);
        const float y1 = dot8a(&W[24], f);
        const float y2 = dot8a(&W[32], f);
        const float y3 = dot8a(&W[40], f);
        const float y4 = dot8a(&W[48], f);
        const float y5 = dot8a(&W[56], f);
        float val = fmaf(u0, y1, y0);
        val = fmaf(u1, y2, val);
        val = fmaf(u0 * u0, y3, val);
        val = fmaf(2.f * u0 * u1, y4, val);
        val = fmaf(u1 * u1, y5, val);
        acc = fmaf(sc, val, acc);
    }

    out[(size_t)v * 256 + c * 8 + i] = acc / fmaxf(ssum, 1e-8f);
}

extern "C" void kernel_launch(void* const* d_in, const int* in_sizes, int n_in,
                              void* d_out, int out_size, void* d_ws, size_t ws_size,
                              hipStream_t stream) {
    const float* x         = (const float*)d_in[0];
    const int*   neighbors = (const int*)d_in[1];
    const void*  maskp     = d_in[2];
    const float* ptm       = (const float*)d_in[3];
    const float* rpu       = (const float*)d_in[4];
    const float* rr        = (const float*)d_in[5];
    const float* vb0       = (const float*)d_in[6];
    const float* vb1       = (const float*)d_in[7];
    const float* vb2       = (const float*)d_in[8];
    const float* qc        = (const float*)d_in[9];
    const float* kc        = (const float*)d_in[10];
    const float* w0p       = (const float*)d_in[11];
    const float* w1p       = (const float*)d_in[12];
    const float* w2p       = (const float*)d_in[13];
    float* out = (float*)d_out;

    int*    flag = (int*)d_ws;
    float4* wtab = (float4*)((char*)d_ws + 1024);   // 64KB table

    detect_mask_kind<<<1, 64, 0, stream>>>((const unsigned int*)maskp, flag);
    compute_weights<<<1, 256, 0, stream>>>(rr, vb0, vb1, vb2,
                                           qc, kc, w0p, w1p, w2p, wtab);
    ge_attn_kernel<<<NV, 256, 0, stream>>>(x, neighbors, maskp, ptm, rpu,
                                           wtab, flag, out);
}

// Round 12
// 359.848 us; speedup vs baseline: 1.5899x; 1.1456x over previous
//
#include <hip/hip_runtime.h>

#define NV   20000
#define MAXN 16

// ---------------------------------------------------------------------------
// Mask dtype detection (bool may arrive as int32 / byte / float32).
// flag: 0 = int32 words, 2 = float32 pattern, 1 = byte bool.
// ---------------------------------------------------------------------------
__global__ void detect_mask_kind(const unsigned int* __restrict__ m,
                                 int* __restrict__ flag) {
    if (threadIdx.x == 0 && blockIdx.x == 0) {
        int allint = 1, allflt = 1;
        #pragma unroll 8
        for (int k = 0; k < 64; ++k) {
            unsigned w = m[k];
            if (!(w == 0u || w == 1u)) allint = 0;
            if (!(w == 0u || w == 0x3F800000u)) allflt = 0;
        }
        *flag = allint ? 0 : (allflt ? 2 : 1);
    }
}

// ---------------------------------------------------------------------------
// One-time weight combine: for each thread slot t=(c,i) produce 8 rows of 8
// (WQ, WK, W0, W1o0, W1o1, W2o0, W2o1, W2o2) = 64 floats, contiguous per t.
// 64KB table, L2-resident, shared by all 20000 main blocks.
// ---------------------------------------------------------------------------
__global__ void compute_weights(const float* __restrict__ rr,
                                const float* __restrict__ vb0,
                                const float* __restrict__ vb1,
                                const float* __restrict__ vb2,
                                const float* __restrict__ qc,
                                const float* __restrict__ kc,
                                const float* __restrict__ w0p,
                                const float* __restrict__ w1p,
                                const float* __restrict__ w2p,
                                float4* __restrict__ wt) {
    const int t = threadIdx.x;
    const int c = t & 31;
    const int i = t >> 5;
    float WQr[8], WKr[8], W0r[8], W1r0[8], W1r1[8], W2r0[8], W2r1[8], W2r2[8];
    #pragma unroll
    for (int j = 0; j < 8; ++j) {
        WQr[j] = 0.f; WKr[j] = 0.f; W0r[j] = 0.f; W1r0[j] = 0.f;
        W1r1[j] = 0.f; W2r0[j] = 0.f; W2r1[j] = 0.f; W2r2[j] = 0.f;
    }
    #pragma unroll
    for (int b = 0; b < 8; ++b) {
        const float qcb = qc[c * 8 + b];
        const float kcb = kc[c * 8 + b];
        const float w0b = w0p[c * 8 + b];
        const float w1b = w1p[c * 8 + b];
        const float w2b = w2p[c * 8 + b];
        const float* rrb = rr  + b * 64  + i * 8;
        const float* z0  = vb0 + b * 64  + i * 8;
        const float* z1  = vb1 + b * 128 + i * 8;   // [b][o][i][j]
        const float* z2  = vb2 + b * 192 + i * 8;
        #pragma unroll
        for (int j = 0; j < 8; ++j) {
            const float r = rrb[j];
            WQr[j]  = fmaf(qcb, r, WQr[j]);
            WKr[j]  = fmaf(kcb, r, WKr[j]);
            W0r[j]  = fmaf(w0b, z0[j],       W0r[j]);
            W1r0[j] = fmaf(w1b, z1[j],       W1r0[j]);
            W1r1[j] = fmaf(w1b, z1[64 + j],  W1r1[j]);
            W2r0[j] = fmaf(w2b, z2[j],       W2r0[j]);
            W2r1[j] = fmaf(w2b, z2[64 + j],  W2r1[j]);
            W2r2[j] = fmaf(w2b, z2[128 + j], W2r2[j]);
        }
    }
    float4* o = wt + t * 16;
    o[ 0] = *(const float4*)&WQr[0];  o[ 1] = *(const float4*)&WQr[4];
    o[ 2] = *(const float4*)&WKr[0];  o[ 3] = *(const float4*)&WKr[4];
    o[ 4] = *(const float4*)&W0r[0];  o[ 5] = *(const float4*)&W0r[4];
    o[ 6] = *(const float4*)&W1r0[0]; o[ 7] = *(const float4*)&W1r0[4];
    o[ 8] = *(const float4*)&W1r1[0]; o[ 9] = *(const float4*)&W1r1[4];
    o[10] = *(const float4*)&W2r0[0]; o[11] = *(const float4*)&W2r0[4];
    o[12] = *(const float4*)&W2r1[0]; o[13] = *(const float4*)&W2r1[4];
    o[14] = *(const float4*)&W2r2[0]; o[15] = *(const float4*)&W2r2[4];
}

__device__ __forceinline__ float dot8a(const float* __restrict__ w,
                                       const float* __restrict__ f) {
    float s = w[0] * f[0];
    #pragma unroll
    for (int j = 1; j < 8; ++j) s = fmaf(w[j], f[j], s);
    return s;
}

__device__ __forceinline__ float dot8f4(const float4& a, const float4& b,
                                        const float* __restrict__ f) {
    return fmaf(a.x, f[0], fmaf(a.y, f[1], fmaf(a.z, f[2], fmaf(a.w, f[3],
           fmaf(b.x, f[4], fmaf(b.y, f[5], fmaf(b.z, f[6], b.w * f[7])))))));
}

// Score reduction via LDS atomics instead of 5-deep shuffle chains (R8-R11:
// VALUBusy pinned at 48% by ds_bpermute latency chains). Per neighbor:
// dot8 -> 2 shfl (depth 2) -> predicated ds_add_f32 from 8 lanes. W usage is
// pass-split (WQ/WK 16 regs early; 48 value rows only in pass B) so peak regs
// ~85 -> launch_bounds(256,5) -> 5 waves/SIMD (R8-R11 stuck at 4 with the
// full 64-reg pin).
__global__ void __launch_bounds__(256, 5)
ge_attn_kernel(const float* __restrict__ x,
               const int*   __restrict__ neighbors,
               const void*  __restrict__ maskp,
               const float* __restrict__ ptm,
               const float* __restrict__ rpu,
               const float4* __restrict__ wt,
               const int*   __restrict__ mflag,
               float*       __restrict__ out) {
    const int t = threadIdx.x;
    const int c = t & 31;   // channel
    const int i = t >> 5;   // rep index 0..7
    const int mf = *mflag;

    // shared transported features: [n][j-pair][c], float2 per slot = 16KB
    __shared__ __align__(16) float2 fsh[16][4][32];
    __shared__ float sqni[16][8];   // Q[n,i] accumulators (pre-relu)
    __shared__ float kk[8];         // K[i]
    __shared__ float sn[16];        // sum_i relu(Q+K) per neighbor
    __shared__ float smask[16];

    const int v  = blockIdx.x;
    const int vq = v * 16;

    // zero score accumulators; load mask (all pre-B1)
    if (t < 128) ((float*)sqni)[t] = 0.f;
    if (t >= 128 && t < 144) sn[t - 128] = 0.f;
    if (t < 16) {
        int mm;
        if (mf == 0)      mm = (((const int*)maskp)[vq + t] != 0);
        else if (mf == 1) mm = (((const unsigned char*)maskp)[vq + t] != 0);
        else              mm = (((const float*)maskp)[vq + t] != 0.0f);
        smask[t] = mm ? 1.f : 0.f;
    }

    // WQ/WK rows only (16 floats pinned) — value rows loaded later
    float WQK[16];
    {
        const float4* wp = wt + t * 16;
        #pragma unroll
        for (int r = 0; r < 4; ++r) {
            const float4 q = wp[r];
            WQK[r * 4 + 0] = q.x; WQK[r * 4 + 1] = q.y;
            WQK[r * 4 + 2] = q.z; WQK[r * 4 + 3] = q.w;
        }
        #pragma unroll
        for (int r = 0; r < 16; ++r)
            asm volatile("" : "+v"(WQK[r]));
    }

    // ---- phase 1 (branch-free): transport n=2i and 2i+1, mask-scaled ----
    #pragma unroll
    for (int sub = 0; sub < 2; ++sub) {
        const int n = 2 * i + sub;
        int mm;
        if (mf == 0)      mm = (((const int*)maskp)[vq + n] != 0);
        else if (mf == 1) mm = (((const unsigned char*)maskp)[vq + n] != 0);
        else              mm = (((const float*)maskp)[vq + n] != 0.0f);
        const float m = mm ? 1.f : 0.f;
        const int nbv = neighbors[vq + n];
        float xn[8];
        {
            const float* xnp = x + (size_t)nbv * 256 + c * 8;
            *(float4*)&xn[0] = *(const float4*)xnp;
            *(float4*)&xn[4] = *(const float4*)(xnp + 4);
        }
        const float4* P4 = (const float4*)(ptm + (size_t)(vq + n) * 64);
        #pragma unroll
        for (int j2 = 0; j2 < 4; ++j2) {
            float2 fo;
            fo.x = dot8f4(P4[4 * j2 + 0], P4[4 * j2 + 1], xn) * m;
            fo.y = dot8f4(P4[4 * j2 + 2], P4[4 * j2 + 3], xn) * m;
            fsh[n][j2][c] = fo;
        }
    }

    // K[i]: one shuffle reduction per vertex (not per neighbor), lane0 -> kk
    {
        float xc[8];
        const float* xv = x + (size_t)v * 256 + c * 8;
        *(float4*)&xc[0] = *(const float4*)xv;
        *(float4*)&xc[4] = *(const float4*)(xv + 4);
        float kp = dot8a(&WQK[8], xc);
        kp += __shfl_xor(kp, 1);
        kp += __shfl_xor(kp, 2);
        kp += __shfl_xor(kp, 4);
        kp += __shfl_xor(kp, 8);
        kp += __shfl_xor(kp, 16);
        if ((t & 31) == 0) kk[i] = kp;
    }

    __syncthreads();   // B1: fsh, zeros, smask, kk

    // ---- pass A: Q[n,i] partials via depth-2 shuffle + LDS atomic ----
    #pragma unroll 4
    for (int n = 0; n < 16; ++n) {
        float f[8];
        #pragma unroll
        for (int j2 = 0; j2 < 4; ++j2) {
            const float2 t2 = fsh[n][j2][c];
            f[2 * j2]     = t2.x;
            f[2 * j2 + 1] = t2.y;
        }
        float q = dot8a(&WQK[0], f);
        q += __shfl_xor(q, 1);
        q += __shfl_xor(q, 2);
        if ((c & 3) == 0) atomicAdd(&sqni[n][i], q);
    }

    // issue value-row loads now (latency hidden across B2/B3)
    float WV[48];
    {
        const float4* wp = wt + t * 16 + 4;
        #pragma unroll
        for (int r = 0; r < 12; ++r) {
            const float4 q = wp[r];
            WV[r * 4 + 0] = q.x; WV[r * 4 + 1] = q.y;
            WV[r * 4 + 2] = q.z; WV[r * 4 + 3] = q.w;
        }
    }

    __syncthreads();   // B2: sqni complete

    // ---- fixup: relu(Q+K) summed over i via LDS atomic ----
    if (t < 128) {
        const int nn = t >> 3, ii = t & 7;
        const float r = fmaxf(sqni[nn][ii] + kk[ii], 0.f);
        atomicAdd(&sn[nn], r);
    }

    __syncthreads();   // B3: sn complete

    #pragma unroll
    for (int r = 0; r < 48; ++r)
        asm volatile("" : "+v"(WV[r]));   // pin value rows for pass B

    // ---- pass B: values + weighted accumulation ----
    float acc = 0.f, ssum = 0.f;
    #pragma unroll 4
    for (int n = 0; n < 16; ++n) {
        const float sc = 0.125f * sn[n] * smask[n];
        ssum += sc;
        float f[8];
        #pragma unroll
        for (int j2 = 0; j2 < 4; ++j2) {
            const float2 t2 = fsh[n][j2][c];
            f[2 * j2]     = t2.x;
            f[2 * j2 + 1] = t2.y;
        }
        const float u0 = rpu[(size_t)(vq + n) * 2];
        const float u1 = rpu[(size_t)(vq + n) * 2 + 1];
        const float y0 = dot8a(&WV[ 0], f);
        const float y1 = dot8a(&WV[ 8], f);
        const float y2 = dot8a(&WV[16], f);
        const float y3 = dot8a(&WV[24], f);
        const float y4 = dot8a(&WV[32], f);
        const float y5 = dot8a(&WV[40], f);
        float val = fmaf(u0, y1, y0);
        val = fmaf(u1, y2, val);
        val = fmaf(u0 * u0, y3, val);
        val = fmaf(2.f * u0 * u1, y4, val);
        val = fmaf(u1 * u1, y5, val);
        acc = fmaf(sc, val, acc);
    }

    out[(size_t)v * 256 + c * 8 + i] = acc / fmaxf(ssum, 1e-8f);
}

extern "C" void kernel_launch(void* const* d_in, const int* in_sizes, int n_in,
                              void* d_out, int out_size, void* d_ws, size_t ws_size,
                              hipStream_t stream) {
    const float* x         = (const float*)d_in[0];
    const int*   neighbors = (const int*)d_in[1];
    const void*  maskp     = d_in[2];
    const float* ptm       = (const float*)d_in[3];
    const float* rpu       = (const float*)d_in[4];
    const float* rr        = (const float*)d_in[5];
    const float* vb0       = (const float*)d_in[6];
    const float* vb1       = (const float*)d_in[7];
    const float* vb2       = (const float*)d_in[8];
    const float* qc        = (const float*)d_in[9];
    const float* kc        = (const float*)d_in[10];
    const float* w0p       = (const float*)d_in[11];
    const float* w1p       = (const float*)d_in[12];
    const float* w2p       = (const float*)d_in[13];
    float* out = (float*)d_out;

    int*    flag = (int*)d_ws;
    float4* wtab = (float4*)((char*)d_ws + 1024);   // 64KB table

    detect_mask_kind<<<1, 64, 0, stream>>>((const unsigned int*)maskp, flag);
    compute_weights<<<1, 256, 0, stream>>>(rr, vb0, vb1, vb2,
                                           qc, kc, w0p, w1p, w2p, wtab);
    ge_attn_kernel<<<NV, 256, 0, stream>>>(x, neighbors, maskp, ptm, rpu,
                                           wtab, flag, out);
}

// Round 13
// 291.515 us; speedup vs baseline: 1.9626x; 1.2344x over previous
//
#include <hip/hip_runtime.h>

#define NV   20000
#define MAXN 16

// ---------------------------------------------------------------------------
// Mask dtype detection (bool may arrive as int32 / byte / float32).
// ---------------------------------------------------------------------------
__global__ void detect_mask_kind(const unsigned int* __restrict__ m,
                                 int* __restrict__ flag) {
    if (threadIdx.x == 0 && blockIdx.x == 0) {
        int allint = 1, allflt = 1;
        #pragma unroll 8
        for (int k = 0; k < 64; ++k) {
            unsigned w = m[k];
            if (!(w == 0u || w == 1u)) allint = 0;
            if (!(w == 0u || w == 0x3F800000u)) allflt = 0;
        }
        *flag = allint ? 0 : (allflt ? 2 : 1);
    }
}

// ---------------------------------------------------------------------------
// One-time weight combine: per thread slot t=(c,i), 8 rows of 8
// (WQ, WK, W0, W1o0, W1o1, W2o0, W2o1, W2o2) = 16 float4 contiguous per t.
// ---------------------------------------------------------------------------
__global__ void compute_weights(const float* __restrict__ rr,
                                const float* __restrict__ vb0,
                                const float* __restrict__ vb1,
                                const float* __restrict__ vb2,
                                const float* __restrict__ qc,
                                const float* __restrict__ kc,
                                const float* __restrict__ w0p,
                                const float* __restrict__ w1p,
                                const float* __restrict__ w2p,
                                float4* __restrict__ wt) {
    const int t = threadIdx.x;
    const int c = t & 31;
    const int i = t >> 5;
    float WQr[8], WKr[8], W0r[8], W1r0[8], W1r1[8], W2r0[8], W2r1[8], W2r2[8];
    #pragma unroll
    for (int j = 0; j < 8; ++j) {
        WQr[j] = 0.f; WKr[j] = 0.f; W0r[j] = 0.f; W1r0[j] = 0.f;
        W1r1[j] = 0.f; W2r0[j] = 0.f; W2r1[j] = 0.f; W2r2[j] = 0.f;
    }
    #pragma unroll
    for (int b = 0; b < 8; ++b) {
        const float qcb = qc[c * 8 + b];
        const float kcb = kc[c * 8 + b];
        const float w0b = w0p[c * 8 + b];
        const float w1b = w1p[c * 8 + b];
        const float w2b = w2p[c * 8 + b];
        const float* rrb = rr  + b * 64  + i * 8;
        const float* z0  = vb0 + b * 64  + i * 8;
        const float* z1  = vb1 + b * 128 + i * 8;   // [b][o][i][j]
        const float* z2  = vb2 + b * 192 + i * 8;
        #pragma unroll
        for (int j = 0; j < 8; ++j) {
            const float r = rrb[j];
            WQr[j]  = fmaf(qcb, r, WQr[j]);
            WKr[j]  = fmaf(kcb, r, WKr[j]);
            W0r[j]  = fmaf(w0b, z0[j],       W0r[j]);
            W1r0[j] = fmaf(w1b, z1[j],       W1r0[j]);
            W1r1[j] = fmaf(w1b, z1[64 + j],  W1r1[j]);
            W2r0[j] = fmaf(w2b, z2[j],       W2r0[j]);
            W2r1[j] = fmaf(w2b, z2[64 + j],  W2r1[j]);
            W2r2[j] = fmaf(w2b, z2[128 + j], W2r2[j]);
        }
    }
    float4* o = wt + t * 16;
    o[ 0] = *(const float4*)&WQr[0];  o[ 1] = *(const float4*)&WQr[4];
    o[ 2] = *(const float4*)&WKr[0];  o[ 3] = *(const float4*)&WKr[4];
    o[ 4] = *(const float4*)&W0r[0];  o[ 5] = *(const float4*)&W0r[4];
    o[ 6] = *(const float4*)&W1r0[0]; o[ 7] = *(const float4*)&W1r0[4];
    o[ 8] = *(const float4*)&W1r1[0]; o[ 9] = *(const float4*)&W1r1[4];
    o[10] = *(const float4*)&W2r0[0]; o[11] = *(const float4*)&W2r0[4];
    o[12] = *(const float4*)&W2r1[0]; o[13] = *(const float4*)&W2r1[4];
    o[14] = *(const float4*)&W2r2[0]; o[15] = *(const float4*)&W2r2[4];
}

__device__ __forceinline__ float dot8a(const float* __restrict__ w,
                                       const float* __restrict__ f) {
    float s = w[0] * f[0];
    #pragma unroll
    for (int j = 1; j < 8; ++j) s = fmaf(w[j], f[j], s);
    return s;
}

__device__ __forceinline__ float dot8f4(const float4& a, const float4& b,
                                        const float* __restrict__ f) {
    return fmaf(a.x, f[0], fmaf(a.y, f[1], fmaf(a.z, f[2], fmaf(a.w, f[3],
           fmaf(b.x, f[4], fmaf(b.y, f[5], fmaf(b.z, f[6], b.w * f[7])))))));
}

// Aggregation-form kernel: out[c,i] = sum_k sum_j Wk[c,i,j] * Fk[c,j] with
// Fk[c,j] = sum_n sc_n * poly_k(u_n) * f'[n,c,j]. Swapping the n and j sums
// cuts the value pipeline from 928 to ~160 FMA/thread (R8-R12 all converged
// at ~360us because total work was constant). Score path = R12's proven
// atomic scheme (depth-3 shfl now). WV rows needed only for the final 48 FMA.
__global__ void __launch_bounds__(256, 5)
ge_attn_kernel(const float* __restrict__ x,
               const int*   __restrict__ neighbors,
               const void*  __restrict__ maskp,
               const float* __restrict__ ptm,
               const float* __restrict__ rpu,
               const float4* __restrict__ wt,
               const int*   __restrict__ mflag,
               float*       __restrict__ out) {
    const int t = threadIdx.x;
    const int c = t & 31;   // channel
    const int i = t >> 5;   // rep index (also the j-slot in aggregation)
    const int mf = *mflag;

    // f' store: [j][c][n], stride-17 pad -> conflict-free for both the
    // pass-A (c,i) reads and the aggregation (c,j) reads.  17.4KB
    __shared__ float fsh2[8][32][17];
    __shared__ float Fsh[8][32][6];   // aggregated features [j][c][k]  6KB
    __shared__ float sqni[16][8];     // Q[n,i] accumulators (pre-relu)
    __shared__ float kk[8];           // K[i]
    __shared__ float sn[16];          // sum_i relu(Q+K)
    __shared__ float smask[16];

    const int v  = blockIdx.x;
    const int vq = v * 16;

    // zero accumulators; mask -> LDS
    if (t < 128) ((float*)sqni)[t] = 0.f;
    else if (t < 144) sn[t - 128] = 0.f;
    if (t < 16) {
        int mm;
        if (mf == 0)      mm = (((const int*)maskp)[vq + t] != 0);
        else if (mf == 1) mm = (((const unsigned char*)maskp)[vq + t] != 0);
        else              mm = (((const float*)maskp)[vq + t] != 0.0f);
        smask[t] = mm ? 1.f : 0.f;
    }

    // WQ/WK rows (16 floats pinned)
    float WQK[16];
    {
        const float4* wp = wt + t * 16;
        #pragma unroll
        for (int r = 0; r < 4; ++r) {
            const float4 q = wp[r];
            WQK[r * 4 + 0] = q.x; WQK[r * 4 + 1] = q.y;
            WQK[r * 4 + 2] = q.z; WQK[r * 4 + 3] = q.w;
        }
        #pragma unroll
        for (int r = 0; r < 16; ++r)
            asm volatile("" : "+v"(WQK[r]));
    }

    // ---- phase 1: transport n=2i,2i+1 (mask-scaled), scatter to fsh2 ----
    #pragma unroll
    for (int sub = 0; sub < 2; ++sub) {
        const int n = 2 * i + sub;
        int mm;
        if (mf == 0)      mm = (((const int*)maskp)[vq + n] != 0);
        else if (mf == 1) mm = (((const unsigned char*)maskp)[vq + n] != 0);
        else              mm = (((const float*)maskp)[vq + n] != 0.0f);
        const float m = mm ? 1.f : 0.f;
        const int nbv = neighbors[vq + n];
        float xn[8];
        {
            const float* xnp = x + (size_t)nbv * 256 + c * 8;
            *(float4*)&xn[0] = *(const float4*)xnp;
            *(float4*)&xn[4] = *(const float4*)(xnp + 4);
        }
        const float4* P4 = (const float4*)(ptm + (size_t)(vq + n) * 64);
        #pragma unroll
        for (int j2 = 0; j2 < 4; ++j2) {
            fsh2[2 * j2    ][c][n] = dot8f4(P4[4 * j2 + 0], P4[4 * j2 + 1], xn) * m;
            fsh2[2 * j2 + 1][c][n] = dot8f4(P4[4 * j2 + 2], P4[4 * j2 + 3], xn) * m;
        }
    }

    // K[i]: one shuffle reduction per vertex
    {
        float xc[8];
        const float* xv = x + (size_t)v * 256 + c * 8;
        *(float4*)&xc[0] = *(const float4*)xv;
        *(float4*)&xc[4] = *(const float4*)(xv + 4);
        float kp = dot8a(&WQK[8], xc);
        kp += __shfl_xor(kp, 1);
        kp += __shfl_xor(kp, 2);
        kp += __shfl_xor(kp, 4);
        kp += __shfl_xor(kp, 8);
        kp += __shfl_xor(kp, 16);
        if ((t & 31) == 0) kk[i] = kp;
    }

    __syncthreads();   // B1

    // ---- pass A: Q[n,i] partials, neighbor pairs for ILP ----
    #pragma unroll 2
    for (int n2 = 0; n2 < 8; ++n2) {
        const int n = 2 * n2;
        float fa[8], fb[8];
        #pragma unroll
        for (int j = 0; j < 8; ++j) {
            fa[j] = fsh2[j][c][n];
            fb[j] = fsh2[j][c][n + 1];
        }
        float qa = dot8a(&WQK[0], fa);
        float qb = dot8a(&WQK[0], fb);
        qa += __shfl_xor(qa, 1);  qb += __shfl_xor(qb, 1);
        qa += __shfl_xor(qa, 2);  qb += __shfl_xor(qb, 2);
        qa += __shfl_xor(qa, 4);  qb += __shfl_xor(qb, 4);
        if ((c & 7) == 0) {
            atomicAdd(&sqni[n][i], qa);
            atomicAdd(&sqni[n + 1][i], qb);
        }
    }

    // issue value-row loads now; consumed only in the final dots
    float WV[48];
    {
        const float4* wp = wt + t * 16 + 4;
        #pragma unroll
        for (int r = 0; r < 12; ++r) {
            const float4 q = wp[r];
            WV[r * 4 + 0] = q.x; WV[r * 4 + 1] = q.y;
            WV[r * 4 + 2] = q.z; WV[r * 4 + 3] = q.w;
        }
    }

    __syncthreads();   // B2: sqni done

    if (t < 128) {
        const int nn = t >> 3, ii = t & 7;
        atomicAdd(&sn[nn], fmaxf(sqni[nn][ii] + kk[ii], 0.f));
    }

    __syncthreads();   // B3: sn done

    #pragma unroll
    for (int r = 0; r < 48; ++r)
        asm volatile("" : "+v"(WV[r]));   // WV resident from here

    // ---- aggregation: thread (c, j=i) builds F0..F5[c,j] over neighbors ----
    float F0 = 0.f, F1 = 0.f, F2 = 0.f, F3 = 0.f, F4 = 0.f, F5 = 0.f;
    float ssum = 0.f;
    #pragma unroll 4
    for (int n2 = 0; n2 < 8; ++n2) {
        const int n = 2 * n2;
        const float sca = 0.125f * sn[n] * smask[n];
        const float scb = 0.125f * sn[n + 1] * smask[n + 1];
        const float u0a = rpu[(size_t)(vq + n) * 2];
        const float u1a = rpu[(size_t)(vq + n) * 2 + 1];
        const float u0b = rpu[(size_t)(vq + n + 1) * 2];
        const float u1b = rpu[(size_t)(vq + n + 1) * 2 + 1];
        const float fa = fsh2[i][c][n];
        const float fb = fsh2[i][c][n + 1];
        ssum += sca + scb;
        const float fsa = fa * sca;
        const float fsb = fb * scb;
        F0 += fsa + fsb;
        F1 = fmaf(u0a, fsa, fmaf(u0b, fsb, F1));
        F2 = fmaf(u1a, fsa, fmaf(u1b, fsb, F2));
        F3 = fmaf(u0a * u0a, fsa, fmaf(u0b * u0b, fsb, F3));
        F4 = fmaf(2.f * u0a * u1a, fsa, fmaf(2.f * u0b * u1b, fsb, F4));
        F5 = fmaf(u1a * u1a, fsa, fmaf(u1b * u1b, fsb, F5));
    }
    *(float2*)&Fsh[i][c][0] = make_float2(F0, F1);
    *(float2*)&Fsh[i][c][2] = make_float2(F2, F3);
    *(float2*)&Fsh[i][c][4] = make_float2(F4, F5);

    __syncthreads();   // B4: Fsh done

    // ---- final: out[c,i] = sum_j sum_k WV[k*8+j] * Fk[c,j], / denom ----
    float a0 = 0.f, a1 = 0.f, a2 = 0.f;
    #pragma unroll
    for (int jj = 0; jj < 8; ++jj) {
        const float2 F01 = *(const float2*)&Fsh[jj][c][0];
        const float2 F23 = *(const float2*)&Fsh[jj][c][2];
        const float2 F45 = *(const float2*)&Fsh[jj][c][4];
        a0 = fmaf(WV[     jj], F01.x, a0);
        a1 = fmaf(WV[ 8 + jj], F01.y, a1);
        a2 = fmaf(WV[16 + jj], F23.x, a2);
        a0 = fmaf(WV[24 + jj], F23.y, a0);
        a1 = fmaf(WV[32 + jj], F45.x, a1);
        a2 = fmaf(WV[40 + jj], F45.y, a2);
    }
    const float acc = a0 + a1 + a2;
    out[(size_t)v * 256 + c * 8 + i] = acc / fmaxf(ssum, 1e-8f);
}

extern "C" void kernel_launch(void* const* d_in, const int* in_sizes, int n_in,
                              void* d_out, int out_size, void* d_ws, size_t ws_size,
                              hipStream_t stream) {
    const float* x         = (const float*)d_in[0];
    const int*   neighbors = (const int*)d_in[1];
    const void*  maskp     = d_in[2];
    const float* ptm       = (const float*)d_in[3];
    const float* rpu       = (const float*)d_in[4];
    const float* rr        = (const float*)d_in[5];
    const float* vb0       = (const float*)d_in[6];
    const float* vb1       = (const float*)d_in[7];
    const float* vb2       = (const float*)d_in[8];
    const float* qc        = (const float*)d_in[9];
    const float* kc        = (const float*)d_in[10];
    const float* w0p       = (const float*)d_in[11];
    const float* w1p       = (const float*)d_in[12];
    const float* w2p       = (const float*)d_in[13];
    float* out = (float*)d_out;

    int*    flag = (int*)d_ws;
    float4* wtab = (float4*)((char*)d_ws + 1024);   // 64KB table

    detect_mask_kind<<<1, 64, 0, stream>>>((const unsigned int*)maskp, flag);
    compute_weights<<<1, 256, 0, stream>>>(rr, vb0, vb1, vb2,
                                           qc, kc, w0p, w1p, w2p, wtab);
    ge_attn_kernel<<<NV, 256, 0, stream>>>(x, neighbors, maskp, ptm, rpu,
                                           wtab, flag, out);
}